// Round 1
// baseline (43.688 us; speedup 1.0000x reference)
//
#include <hip/hip_runtime.h>

// Problem constants (from reference)
#define B_SAMPLES 16384
#define NFEATS    32
#define D         128     // LPA
#define VOCAB     262144  // N_FEATS * GROUP_SIZE
#define GROUP     8192

// One wave (64 lanes) per sample.
//  - lanes [0..31]  handle even features, lanes [32..63] odd features
//  - each half-wave reads a full 512B embedding row as 32 x float4
//  - 16 unrolled iterations cover all 32 features
//  - halves merged with shfl_xor(32); epilogue fully in registers
__global__ __launch_bounds__(256) void nnue_fused(
    const int*   __restrict__ fidx,     // [B, 32]
    const int*   __restrict__ ply,      // [B]
    const float* __restrict__ emb,      // [3*VOCAB, 128]
    const float* __restrict__ pa_bias,  // [3, 128]
    const float* __restrict__ w_out,    // [30, 128]
    const float* __restrict__ b_out,    // [30]
    float*       __restrict__ out)      // [B]
{
    const int wave = threadIdx.x >> 6;
    const int lane = threadIdx.x & 63;
    const int s    = (blockIdx.x << 2) + wave;

    const int p    = ply[s];        // 0..29
    const int pa   = p / 10;        // phase bucket 0..2
    const int half = lane >> 5;     // feature parity handled by this half-wave
    const int l    = lane & 31;     // float4 slot within the 128-float row

    const int*   fi      = fidx + s * NFEATS;
    const float* embbase = emb + (size_t)pa * VOCAB * D;

    float4 acc = make_float4(0.f, 0.f, 0.f, 0.f);

#pragma unroll
    for (int f0 = 0; f0 < NFEATS; f0 += 2) {
        const int f   = f0 + half;
        const int row = f * GROUP + fi[f];             // index into this phase bucket
        const float4* rp = (const float4*)(embbase + (size_t)row * D);
        const float4 v = rp[l];
        acc.x += v.x; acc.y += v.y; acc.z += v.z; acc.w += v.w;
    }

    // merge the two half-wave partial sums (lane l and l+32 hold same positions)
    acc.x += __shfl_xor(acc.x, 32);
    acc.y += __shfl_xor(acc.y, 32);
    acc.z += __shfl_xor(acc.z, 32);
    acc.w += __shfl_xor(acc.w, 32);

    // bias + clip + per-ply head dot product
    const float4 bv = ((const float4*)(pa_bias + pa * D))[l];
    const float4 wv = ((const float4*)(w_out  + p  * D))[l];

    float dot = 0.f, x;
    x = fminf(fmaxf(acc.x + bv.x, 0.f), 1.f); dot = fmaf(x, wv.x, dot);
    x = fminf(fmaxf(acc.y + bv.y, 0.f), 1.f); dot = fmaf(x, wv.y, dot);
    x = fminf(fmaxf(acc.z + bv.z, 0.f), 1.f); dot = fmaf(x, wv.z, dot);
    x = fminf(fmaxf(acc.w + bv.w, 0.f), 1.f); dot = fmaf(x, wv.w, dot);

    // reduce across 32 lanes (both halves hold identical values post-merge)
    dot += __shfl_xor(dot, 1);
    dot += __shfl_xor(dot, 2);
    dot += __shfl_xor(dot, 4);
    dot += __shfl_xor(dot, 8);
    dot += __shfl_xor(dot, 16);

    if (lane == 0) out[s] = dot + b_out[p];
}

extern "C" void kernel_launch(void* const* d_in, const int* in_sizes, int n_in,
                              void* d_out, int out_size, void* d_ws, size_t ws_size,
                              hipStream_t stream) {
    const int*   fidx    = (const int*)  d_in[0];  // feature_indices [B,32]
    const int*   ply     = (const int*)  d_in[1];  // ply [B]
    // d_in[2] = feature_offsets (recomputed inline as f*GROUP)
    const float* emb     = (const float*)d_in[3];  // [3*VOCAB, 128]
    const float* pa_bias = (const float*)d_in[4];  // [3, 128]
    const float* w_out   = (const float*)d_in[5];  // [30, 128]
    const float* b_out   = (const float*)d_in[6];  // [30]
    float*       out     = (float*)d_out;          // [B]

    // 4 waves per 256-thread block, one wave per sample
    nnue_fused<<<B_SAMPLES / 4, 256, 0, stream>>>(fidx, ply, emb, pa_bias,
                                                  w_out, b_out, out);
}